// Round 13
// baseline (103.240 us; speedup 1.0000x reference)
//
#include <hip/hip_runtime.h>
#include <math.h>

// HeadAttention B=4, S=4096, D=1024, DK=DV=64, fp32 in/out, causal.
// Round 13: X page-span fix. All 12 prior proj variants pinned at 82-120us
// with X delivery ~2.4 TB/s -- the shared invariant was 256-B sequential
// spans per 4KB page (64-row tiles x BK*4B). Now BK_fetch=256: each wave
// fetches its 16 rows x 1KB in 16 paired asm b128s (full 1KB sequential
// coverage per row, all in flight), held in 64 VGPRs, consumed over 4
// BK=64 MFMA steps. W unchanged: block-shared LDS (196 MB total), staged
// per-step with a unified per-superstep vmcnt ledger (12/8/4/0).
// attn / combine / wsplit unchanged.

#define SEQ 4096
#define DIM 1024
#define HD  64
#define NB  4
#define NSPLIT 4

typedef __attribute__((ext_vector_type(4))) float    f32x4;
typedef __attribute__((ext_vector_type(8))) _Float16 f16x8;
typedef __attribute__((ext_vector_type(4))) _Float16 f16x4;

#define MFMA16 __builtin_amdgcn_mfma_f32_16x16x32_f16

// 16B asm load, compile-time byte offset ("=&v": dest never aliases addr)
#define GLD16(dst, ptr, imm)                                        \
  asm volatile("global_load_dwordx4 %0, %1, off offset:" #imm      \
               : "=&v"(dst) : "v"(ptr))

// counted VMEM wait + scheduling fence (rule #18)
#define VMWAIT(n)                                                   \
  do {                                                              \
    asm volatile("s_waitcnt vmcnt(" #n ")" ::: "memory");           \
    __builtin_amdgcn_sched_barrier(0);                              \
  } while (0)

// drain LDS writes, then block barrier (prefetch loads stay in flight)
#define LGKMBAR()                                                   \
  do {                                                              \
    asm volatile("s_waitcnt lgkmcnt(0)" ::: "memory");              \
    __builtin_amdgcn_sched_barrier(0);                              \
    asm volatile("s_barrier" ::: "memory");                         \
    __builtin_amdgcn_sched_barrier(0);                              \
  } while (0)

// swizzled offset into a [row][64] f16 LDS tile (attn): XOR 16B-chunk with row&7
__device__ __forceinline__ int SW(int row, int k) {
  return row * 64 + (k ^ ((row & 7) << 3));
}

// ---------- W pre-split into fragment-linear layout ------------------------
// wf[((which*16+kt)*16 + slot)*512 + lane*8 + j]:
//   slot s=ks*4+ct (0..7) hi-frag, s+8 lo-frag;
//   element = W[k][col]*scale, col=ct*16+(lane&15), k=kt*64+ks*32+(lane>>4)*8+j
__global__ __launch_bounds__(256) void wsplit_kernel(
    const float* __restrict__ Wq, const float* __restrict__ Wk,
    const float* __restrict__ Wv, _Float16* __restrict__ wf)
{
  const int which = blockIdx.x;   // 0..2
  const int kt    = blockIdx.y;   // 0..15
  const float* __restrict__ W = (which == 0) ? Wq : (which == 1) ? Wk : Wv;
  const float scale = (which == 0) ? 0.18033688011112042f : 1.0f;  // log2(e)/8
  const size_t tb = ((size_t)which * 16 + kt) * 8192;
#pragma unroll
  for (int i = 0; i < 2; ++i) {
    const int pair = threadIdx.x + 256 * i;   // 0..511
    const int lane = pair & 63, f = pair >> 6;  // f = ks*4+ct in 0..7
    const int ks = f >> 2, ct = f & 3;
    const int col = ct * 16 + (lane & 15);
    const int k0 = kt * 64 + ks * 32 + (lane >> 4) * 8;
    f16x8 hv, lv;
#pragma unroll
    for (int j = 0; j < 8; ++j) {
      const float y = W[(size_t)(k0 + j) * HD + col] * scale;
      const _Float16 h = (_Float16)y;
      hv[j] = h;
      lv[j] = (_Float16)(y - (float)h);
    }
    *(f16x8*)&wf[tb + (size_t)f * 512 + lane * 8]       = hv;
    *(f16x8*)&wf[tb + (size_t)(8 + f) * 512 + lane * 8] = lv;
  }
}

// ---------- projection: 1KB-span X-in-regs, LDS-shared W -------------------
// grid (256, 3), 256 threads (4 waves, 64 output rows). 4 supersteps of
// K=256; per superstep: 16 X asm loads (A-frag layout, 1KB/row sequential)
// + 4x4 W asm loads; unified vmcnt ledger 12/8/4/0; 4 BK=64 MFMA steps,
// each: ds_write W -> lgkm+s_barrier -> 8 ds_read_b128 W + 12 MFMA.
__global__ __launch_bounds__(256, 2) void proj_kernel(
    const float* __restrict__ Xq, const float* __restrict__ Xk,
    const float* __restrict__ Xv,
    const _Float16* __restrict__ wf,
    _Float16* __restrict__ qh, _Float16* __restrict__ ql,
    _Float16* __restrict__ kh, _Float16* __restrict__ kl,
    _Float16* __restrict__ vt)
{
  __shared__ __attribute__((aligned(16))) _Float16 Ws[2][8192];   // 16 KB ea

  const int which = blockIdx.y;
  const float* __restrict__ X = (which == 0) ? Xq : (which == 1) ? Xk : Xv;

  const int t = threadIdx.x, lane = t & 63, w = t >> 6;
  const int bm = blockIdx.x * 64;

  // X A-frag base: row = bm + w*16 + (lane&15); k-slice = (lane>>4)*8
  const float* xb = X + (size_t)(bm + w * 16 + (lane & 15)) * DIM
                      + ((lane >> 4) * 8);
  // W: thread covers slabs w*4..w*4+3 (1 KB apart) of the 16 KB tile
  const _Float16* gW0 = wf + (size_t)which * 131072 + (w * 4) * 512 + lane * 8;
  int wdst[4];
#pragma unroll
  for (int i = 0; i < 4; ++i) wdst[i] = (w * 4 + i) * 512 + lane * 8;

  f32x4 acc[4] = {{0,0,0,0},{0,0,0,0},{0,0,0,0},{0,0,0,0}};
  f32x4 xr[16];                       // whole superstep's X (const-indexed)
  f16x8 wrA[4], wrB[4], wrC[4], wrD[4];

#define WWRITE(wr, buf)                                              \
  do {                                                               \
    _Pragma("unroll")                                                \
    for (int i = 0; i < 4; ++i) *(f16x8*)&Ws[buf][wdst[i]] = wr[i];  \
  } while (0)

  // compute one BK=64 tile: X chunks xr[base..base+3], W from Ws[buf]
#define COMPT(buf, base)                                                  \
  do {                                                                    \
    _Pragma("unroll")                                                     \
    for (int ks = 0; ks < 2; ++ks) {                                      \
      f32x4 x0 = xr[(base) + 2 * ks];                                     \
      f32x4 x1 = xr[(base) + 2 * ks + 1];                                 \
      f16x8 xh, xl;                                                       \
      _Pragma("unroll")                                                   \
      for (int j = 0; j < 4; ++j) {                                       \
        const _Float16 h0 = (_Float16)x0[j];                              \
        xh[j] = h0; xl[j] = (_Float16)(x0[j] - (float)h0);                \
        const _Float16 h1 = (_Float16)x1[j];                              \
        xh[j + 4] = h1; xl[j + 4] = (_Float16)(x1[j] - (float)h1);        \
      }                                                                   \
      _Pragma("unroll")                                                   \
      for (int ct = 0; ct < 4; ++ct) {                                    \
        f16x8 bh = *(const f16x8*)&Ws[buf][(ks * 4 + ct) * 512 + lane * 8];       \
        f16x8 bl = *(const f16x8*)&Ws[buf][(8 + ks * 4 + ct) * 512 + lane * 8];   \
        acc[ct] = MFMA16(xh, bh, acc[ct], 0, 0, 0);                       \
        acc[ct] = MFMA16(xl, bh, acc[ct], 0, 0, 0);                       \
        acc[ct] = MFMA16(xh, bl, acc[ct], 0, 0, 0);                       \
      }                                                                   \
    }                                                                     \
  } while (0)

#pragma unroll 1
  for (int ss = 0; ss < 4; ++ss) {
    // ---- issue the superstep's 16 X loads (1 KB sequential per row)
    const float* xs = xb + ss * 256;
    GLD16(xr[0],  xs, 0);    GLD16(xr[1],  xs, 16);
    GLD16(xr[2],  xs, 128);  GLD16(xr[3],  xs, 144);
    GLD16(xr[4],  xs, 256);  GLD16(xr[5],  xs, 272);
    GLD16(xr[6],  xs, 384);  GLD16(xr[7],  xs, 400);
    GLD16(xr[8],  xs, 512);  GLD16(xr[9],  xs, 528);
    GLD16(xr[10], xs, 640);  GLD16(xr[11], xs, 656);
    GLD16(xr[12], xs, 768);  GLD16(xr[13], xs, 784);
    GLD16(xr[14], xs, 896);  GLD16(xr[15], xs, 912);
    // ---- issue the 4 W tiles (4 loads each)
    const _Float16* wt0 = gW0 + (size_t)(4 * ss) * 8192;
    const _Float16* wt1 = wt0 + 8192;
    const _Float16* wt2 = wt0 + 16384;
    const _Float16* wt3 = wt0 + 24576;
    GLD16(wrA[0], wt0, 0); GLD16(wrA[1], wt0, 1024);
    GLD16(wrA[2], wt0, 2048); GLD16(wrA[3], wt0, 3072);
    GLD16(wrB[0], wt1, 0); GLD16(wrB[1], wt1, 1024);
    GLD16(wrB[2], wt1, 2048); GLD16(wrB[3], wt1, 3072);
    GLD16(wrC[0], wt2, 0); GLD16(wrC[1], wt2, 1024);
    GLD16(wrC[2], wt2, 2048); GLD16(wrC[3], wt2, 3072);
    GLD16(wrD[0], wt3, 0); GLD16(wrD[1], wt3, 1024);
    GLD16(wrD[2], wt3, 2048); GLD16(wrD[3], wt3, 3072);

    // ---- 4 compute steps; ledger: 32 outstanding -> 12/8/4/0
    VMWAIT(12);                 // X + W0 complete
    WWRITE(wrA, 0);  LGKMBAR();  COMPT(0, 0);
    VMWAIT(8);                  // W1 complete
    WWRITE(wrB, 1);  LGKMBAR();  COMPT(1, 4);
    VMWAIT(4);                  // W2 complete
    WWRITE(wrC, 0);  LGKMBAR();  COMPT(0, 8);
    VMWAIT(0);                  // W3 complete
    WWRITE(wrD, 1);  LGKMBAR();  COMPT(1, 12);
  }
#undef WWRITE
#undef COMPT

  // epilogue: C layout col=lane&15, row=(lane>>4)*4+r
  const size_t orow0 = (size_t)bm + w * 16 + (lane >> 4) * 4;
  if (which < 2) {
    _Float16* oh = (which == 0) ? qh : kh;
    _Float16* ol = (which == 0) ? ql : kl;
#pragma unroll
    for (int ct = 0; ct < 4; ++ct)
#pragma unroll
      for (int r = 0; r < 4; ++r) {
        const float y = acc[ct][r];
        const _Float16 h = (_Float16)y;
        const size_t idx = (orow0 + r) * HD + ct * 16 + (lane & 15);
        oh[idx] = h;
        ol[idx] = (_Float16)(y - (float)h);
      }
  } else {
    const int batch = (int)(orow0 >> 12);
    const int pos = (int)(orow0 & 4095);
#pragma unroll
    for (int ct = 0; ct < 4; ++ct) {
      f16x4 hv;
#pragma unroll
      for (int r = 0; r < 4; ++r) hv[r] = (_Float16)acc[ct][r];
      *(f16x4*)&vt[((size_t)batch * HD + ct * 16 + (lane & 15)) * SEQ + pos] = hv;
    }
  }
}

// ---------- flash attention, fp16x3 QK + f16 PV, split-4 partials ----------
// grid (128, 4): x -> pair p=x>>2 (q-blocks p and 63-p), parity s=x&3.
__global__ __launch_bounds__(256) void attn_kernel(
    const _Float16* __restrict__ qh, const _Float16* __restrict__ ql,
    const _Float16* __restrict__ kh, const _Float16* __restrict__ kl,
    const _Float16* __restrict__ vt,
    _Float16* __restrict__ opart, float* __restrict__ mlp)
{
  __shared__ __attribute__((aligned(16))) _Float16 Ksh[64 * 64];
  __shared__ __attribute__((aligned(16))) _Float16 Ksl[64 * 64];
  __shared__ __attribute__((aligned(16))) _Float16 Vs [64 * 64];
  __shared__ __attribute__((aligned(16))) _Float16 Pt [64 * 64];

  const int t = threadIdx.x, lane = t & 63, w = t >> 6;
  const int b = blockIdx.y;
  const int p = blockIdx.x >> 2, s = blockIdx.x & 3;
  const size_t bS = (size_t)b * SEQ;

  for (int sel = 0; sel < 2; ++sel) {
    const int qb = sel ? (63 - p) : p;
    const int qrow0 = qb * 64 + w * 16;
    const int nt = (qb >= s) ? ((qb - s) >> 2) + 1 : 0;  // kv tiles ≡ s mod 4

    float m[4] = {-INFINITY, -INFINITY, -INFINITY, -INFINITY};
    float lsum[4] = {0.f, 0.f, 0.f, 0.f};
    f32x4 o[4] = {{0,0,0,0},{0,0,0,0},{0,0,0,0},{0,0,0,0}};

    if (nt > 0) {
      const _Float16* qhp = qh + (bS + qrow0 + (lane & 15)) * HD + ((lane >> 4) * 8);
      const _Float16* qlp = ql + (bS + qrow0 + (lane & 15)) * HD + ((lane >> 4) * 8);
      f16x8 qhf[2], qlf[2];
      qhf[0] = *(const f16x8*)(qhp);      qhf[1] = *(const f16x8*)(qhp + 32);
      qlf[0] = *(const f16x8*)(qlp);      qlf[1] = *(const f16x8*)(qlp + 32);

      for (int i = 0; i < nt; ++i) {
        const int kt = s + 4 * i;
        const int j0 = kt * 64;

        __syncthreads();  // previous tile's LDS reads complete
#pragma unroll
        for (int c = 0; c < 2; ++c) {
          const int lin = t + 256 * c;
          const int row = lin >> 3, d8 = (lin & 7) * 8;
          const int dst = SW(row, d8);
          *(f16x8*)&Ksh[dst] = *(const f16x8*)&kh[(bS + j0 + row) * HD + d8];
          *(f16x8*)&Ksl[dst] = *(const f16x8*)&kl[(bS + j0 + row) * HD + d8];
          *(f16x8*)&Vs[dst]  = *(const f16x8*)&vt[((size_t)b * HD + row) * SEQ + j0 + d8];
        }
        __syncthreads();

        // ---- QK^T: fp16x3
        f32x4 sacc[4] = {{0,0,0,0},{0,0,0,0},{0,0,0,0},{0,0,0,0}};
#pragma unroll
        for (int kk = 0; kk < 2; ++kk)
#pragma unroll
          for (int kt4 = 0; kt4 < 4; ++kt4) {
            const int ba = SW(kt4 * 16 + (lane & 15), kk * 32 + (lane >> 4) * 8);
            f16x8 bh = *(const f16x8*)&Ksh[ba];
            f16x8 bl = *(const f16x8*)&Ksl[ba];
            sacc[kt4] = MFMA16(qhf[kk], bh, sacc[kt4], 0, 0, 0);
            sacc[kt4] = MFMA16(qlf[kk], bh, sacc[kt4], 0, 0, 0);
            sacc[kt4] = MFMA16(qhf[kk], bl, sacc[kt4], 0, 0, 0);
          }

        // ---- causal mask on the diagonal tile
        if (kt == qb) {
#pragma unroll
          for (int kt4 = 0; kt4 < 4; ++kt4) {
            const int key = j0 + kt4 * 16 + (lane & 15);
#pragma unroll
            for (int r = 0; r < 4; ++r)
              if (key > qrow0 + (lane >> 4) * 4 + r) sacc[kt4][r] = -INFINITY;
          }
        }

        // ---- online softmax (exp2 domain), P -> LDS f16
        float alf[4];
#pragma unroll
        for (int r = 0; r < 4; ++r) {
          float mx = fmaxf(fmaxf(sacc[0][r], sacc[1][r]),
                           fmaxf(sacc[2][r], sacc[3][r]));
          mx = fmaxf(mx, __shfl_xor(mx, 1));
          mx = fmaxf(mx, __shfl_xor(mx, 2));
          mx = fmaxf(mx, __shfl_xor(mx, 4));
          mx = fmaxf(mx, __shfl_xor(mx, 8));
          const float mn = fmaxf(m[r], mx);
          const float al = exp2f(m[r] - mn);
          const int prow = w * 16 + (lane >> 4) * 4 + r;
          float ps = 0.f;
#pragma unroll
          for (int kt4 = 0; kt4 < 4; ++kt4) {
            const _Float16 ph = (_Float16)exp2f(sacc[kt4][r] - mn);
            ps += (float)ph;
            Pt[SW(prow, kt4 * 16 + (lane & 15))] = ph;
          }
          ps += __shfl_xor(ps, 1);
          ps += __shfl_xor(ps, 2);
          ps += __shfl_xor(ps, 4);
          ps += __shfl_xor(ps, 8);
          lsum[r] = lsum[r] * al + ps;
          m[r] = mn;
          alf[r] = al;
        }
        const f32x4 av = {alf[0], alf[1], alf[2], alf[3]};
#pragma unroll
        for (int ct = 0; ct < 4; ++ct) o[ct] *= av;

        // ---- PV (per-wave Pt region)
#pragma unroll
        for (int kk = 0; kk < 2; ++kk) {
          f16x8 pa = *(const f16x8*)&Pt[SW(w * 16 + (lane & 15),
                                           kk * 32 + (lane >> 4) * 8)];
#pragma unroll
          for (int ct = 0; ct < 4; ++ct) {
            f16x8 vb = *(const f16x8*)&Vs[SW(ct * 16 + (lane & 15),
                                             kk * 32 + (lane >> 4) * 8)];
            o[ct] = MFMA16(pa, vb, o[ct], 0, 0, 0);
          }
        }
      }
    }

    // ---- write partials: normalized o (f16) + (m, l) f32
    f32x4 invv;
#pragma unroll
    for (int r = 0; r < 4; ++r) invv[r] = (nt > 0) ? 1.0f / lsum[r] : 0.0f;
    const size_t ridx0 = (size_t)(b * NSPLIT + s) * SEQ + qrow0 + (lane >> 4) * 4;
#pragma unroll
    for (int ct = 0; ct < 4; ++ct)
#pragma unroll
      for (int r = 0; r < 4; ++r)
        opart[(ridx0 + r) * HD + ct * 16 + (lane & 15)] =
            (_Float16)(o[ct][r] * invv[r]);
    if ((lane & 15) == 0) {
#pragma unroll
      for (int r = 0; r < 4; ++r) {
        mlp[(ridx0 + r) * 2]     = m[r];
        mlp[(ridx0 + r) * 2 + 1] = lsum[r];
      }
    }
  }
}

// ---------- combine the 4 kv-parity partials -------------------------------
__global__ __launch_bounds__(256) void combine_kernel(
    const _Float16* __restrict__ opart, const float* __restrict__ mlp,
    float* __restrict__ out)
{
  const int g = blockIdx.x * 256 + threadIdx.x;   // 262144
  const int row = g >> 4;
  const int cq = (g & 15) * 4;
  const int b = row >> 12, pos = row & 4095;

  float mv[4], lv[4], msx = -INFINITY;
#pragma unroll
  for (int s = 0; s < 4; ++s) {
    const size_t ri = (size_t)(b * NSPLIT + s) * SEQ + pos;
    mv[s] = mlp[ri * 2];
    lv[s] = mlp[ri * 2 + 1];
    msx = fmaxf(msx, mv[s]);
  }
  f32x4 num = {0.f, 0.f, 0.f, 0.f};
  float L = 0.f;
#pragma unroll
  for (int s = 0; s < 4; ++s) {
    const float wgt = lv[s] * exp2f(mv[s] - msx);
    L += wgt;
    const size_t ri = (size_t)(b * NSPLIT + s) * SEQ + pos;
    const f16x4 ov = *(const f16x4*)&opart[ri * HD + cq];
#pragma unroll
    for (int j = 0; j < 4; ++j) num[j] += wgt * (float)ov[j];
  }
  const float inv = 1.0f / L;
  f32x4 res = {num[0] * inv, num[1] * inv, num[2] * inv, num[3] * inv};
  *(f32x4*)&out[(size_t)row * HD + cq] = res;
}

extern "C" void kernel_launch(void* const* d_in, const int* in_sizes, int n_in,
                              void* d_out, int out_size, void* d_ws, size_t ws_size,
                              hipStream_t stream) {
  const float* query = (const float*)d_in[0];
  const float* key   = (const float*)d_in[1];
  const float* value = (const float*)d_in[2];
  const float* Wq    = (const float*)d_in[3];
  const float* Wk    = (const float*)d_in[4];
  const float* Wv    = (const float*)d_in[5];
  // d_in[6]: causal mask, handled analytically.

  float* out = (float*)d_out;

  _Float16* qh  = (_Float16*)d_ws;
  _Float16* ql  = qh  + (size_t)NB * SEQ * HD;
  _Float16* kh  = ql  + (size_t)NB * SEQ * HD;
  _Float16* kl  = kh  + (size_t)NB * SEQ * HD;
  _Float16* vt  = kl  + (size_t)NB * SEQ * HD;           // [b][64][4096]
  _Float16* wf  = vt  + (size_t)NB * SEQ * HD;           // [3][16][16][512]
  _Float16* opart = wf + (size_t)3 * 16 * 8192;          // [b*4+s][4096][64]
  float* mlp = (float*)(opart + (size_t)NB * NSPLIT * SEQ * HD);

  wsplit_kernel<<<dim3(3, 16), 256, 0, stream>>>(Wq, Wk, Wv, wf);
  proj_kernel<<<dim3(256, 3), 256, 0, stream>>>(query, key, value, wf,
                                                qh, ql, kh, kl, vt);
  attn_kernel<<<dim3(128, NB), 256, 0, stream>>>(qh, ql, kh, kl, vt, opart, mlp);
  combine_kernel<<<1024, 256, 0, stream>>>(opart, mlp, out);
}

// Round 14
// 97.436 us; speedup vs baseline: 1.0596x; 1.0596x over previous
//
#include <hip/hip_runtime.h>
#include <math.h>

// HeadAttention B=4, S=4096, D=1024, DK=DV=64, fp32 in/out, causal.
// Round 14: proj work-density fix. All ~82us variants shared M=64/block
// (~350cy compute per barrier-step vs fixed per-step overheads). Now
// M=128, 8 waves/block (512 thr): 2x compute per step, W traffic halved
// (196->98 MB), all 384 blocks co-resident. X direct-to-reg A-frag
// (R13-proven, no X LDS round-trip); W block-shared LDS with asm depth-2
// counted vmcnt ledger (6 loads/step, load-after-compute preserves the
// named reg sets). attn / combine / wsplit unchanged.

#define SEQ 4096
#define DIM 1024
#define HD  64
#define NB  4
#define NSPLIT 4

typedef __attribute__((ext_vector_type(4))) float    f32x4;
typedef __attribute__((ext_vector_type(8))) _Float16 f16x8;
typedef __attribute__((ext_vector_type(4))) _Float16 f16x4;

#define MFMA16 __builtin_amdgcn_mfma_f32_16x16x32_f16

// 16B asm load, compile-time byte offset ("=&v": dest never aliases addr)
#define GLD16(dst, ptr, imm)                                        \
  asm volatile("global_load_dwordx4 %0, %1, off offset:" #imm      \
               : "=&v"(dst) : "v"(ptr))

// counted VMEM wait + scheduling fence (rule #18)
#define VMWAIT(n)                                                   \
  do {                                                              \
    asm volatile("s_waitcnt vmcnt(" #n ")" ::: "memory");           \
    __builtin_amdgcn_sched_barrier(0);                              \
  } while (0)

// drain LDS writes, then block barrier (prefetch loads stay in flight)
#define LGKMBAR()                                                   \
  do {                                                              \
    asm volatile("s_waitcnt lgkmcnt(0)" ::: "memory");              \
    __builtin_amdgcn_sched_barrier(0);                              \
    asm volatile("s_barrier" ::: "memory");                         \
    __builtin_amdgcn_sched_barrier(0);                              \
  } while (0)

// swizzled offset into a [row][64] f16 LDS tile (attn): XOR 16B-chunk with row&7
__device__ __forceinline__ int SW(int row, int k) {
  return row * 64 + (k ^ ((row & 7) << 3));
}

// ---------- W pre-split into fragment-linear layout ------------------------
// wf[((which*16+kt)*16 + slot)*512 + lane*8 + j]:
//   slot s=ks*4+ct (0..7) hi-frag, s+8 lo-frag;
//   element = W[k][col]*scale, col=ct*16+(lane&15), k=kt*64+ks*32+(lane>>4)*8+j
__global__ __launch_bounds__(256) void wsplit_kernel(
    const float* __restrict__ Wq, const float* __restrict__ Wk,
    const float* __restrict__ Wv, _Float16* __restrict__ wf)
{
  const int which = blockIdx.x;   // 0..2
  const int kt    = blockIdx.y;   // 0..15
  const float* __restrict__ W = (which == 0) ? Wq : (which == 1) ? Wk : Wv;
  const float scale = (which == 0) ? 0.18033688011112042f : 1.0f;  // log2(e)/8
  const size_t tb = ((size_t)which * 16 + kt) * 8192;
#pragma unroll
  for (int i = 0; i < 2; ++i) {
    const int pair = threadIdx.x + 256 * i;   // 0..511
    const int lane = pair & 63, f = pair >> 6;  // f = ks*4+ct in 0..7
    const int ks = f >> 2, ct = f & 3;
    const int col = ct * 16 + (lane & 15);
    const int k0 = kt * 64 + ks * 32 + (lane >> 4) * 8;
    f16x8 hv, lv;
#pragma unroll
    for (int j = 0; j < 8; ++j) {
      const float y = W[(size_t)(k0 + j) * HD + col] * scale;
      const _Float16 h = (_Float16)y;
      hv[j] = h;
      lv[j] = (_Float16)(y - (float)h);
    }
    *(f16x8*)&wf[tb + (size_t)f * 512 + lane * 8]       = hv;
    *(f16x8*)&wf[tb + (size_t)(8 + f) * 512 + lane * 8] = lv;
  }
}

// ---------- projection: M=128, 8 waves, X-in-regs, LDS-shared W ------------
// grid (128, 3), 512 threads (8 waves x 16 rows). 16 K-steps of 64.
// Per step/thread: 4 X asm loads (A-frag direct) + 2 W asm loads; ledger
// depth-2 (12 outstanding, vmcnt(6)); 2 ds_write_b128 W; lgkm+s_barrier;
// 8 ds_read_b128 W + 24 MFMA + split VALU. LDS 32 KB (W dbuf only).
__global__ __launch_bounds__(512, 4) void proj_kernel(
    const float* __restrict__ Xq, const float* __restrict__ Xk,
    const float* __restrict__ Xv,
    const _Float16* __restrict__ wf,
    _Float16* __restrict__ qh, _Float16* __restrict__ ql,
    _Float16* __restrict__ kh, _Float16* __restrict__ kl,
    _Float16* __restrict__ vt)
{
  __shared__ __attribute__((aligned(16))) _Float16 Ws[2][8192];   // 16 KB ea

  const int which = blockIdx.y;
  const float* __restrict__ X = (which == 0) ? Xq : (which == 1) ? Xk : Xv;

  const int t = threadIdx.x, lane = t & 63, w = t >> 6;   // w in 0..7
  const int bm = blockIdx.x * 128;

  // X A-frag base: row = bm + w*16 + (lane&15); k-slice = (lane>>4)*8
  const float* xb = X + (size_t)(bm + w * 16 + (lane & 15)) * DIM
                      + ((lane >> 4) * 8);
  // W: thread covers 32 B of the 16 KB tile at element 16*t (two f16x8)
  const _Float16* gW = wf + (size_t)which * 131072 + 16 * t;
  const int wd = 16 * t;

  f32x4 acc[4] = {{0,0,0,0},{0,0,0,0},{0,0,0,0},{0,0,0,0}};
  // named staging sets (rule #20)
  f32x4 xA[4], xB[4];
  f16x8 wA[2], wB[2];

#define LOADT(xs, ws, kt)                                            \
  do {                                                               \
    const float* xp = xb + (kt) * 64;                                \
    GLD16(xs[0], xp, 0);                                             \
    GLD16(xs[1], xp, 16);                                            \
    GLD16(xs[2], xp, 128);                                           \
    GLD16(xs[3], xp, 144);                                           \
    const _Float16* wp = gW + (size_t)(kt) * 8192;                   \
    GLD16(ws[0], wp, 0);                                             \
    GLD16(ws[1], wp, 16);                                            \
  } while (0)

#define WWRITE(ws, buf)                                              \
  do {                                                               \
    *(f16x8*)&Ws[buf][wd]     = ws[0];                               \
    *(f16x8*)&Ws[buf][wd + 8] = ws[1];                               \
  } while (0)

#define COMPUTET(xs, buf)                                                 \
  do {                                                                    \
    _Pragma("unroll")                                                     \
    for (int ks = 0; ks < 2; ++ks) {                                      \
      f32x4 x0 = xs[2 * ks];                                              \
      f32x4 x1 = xs[2 * ks + 1];                                          \
      f16x8 xh, xl;                                                       \
      _Pragma("unroll")                                                   \
      for (int j = 0; j < 4; ++j) {                                       \
        const _Float16 h0 = (_Float16)x0[j];                              \
        xh[j] = h0; xl[j] = (_Float16)(x0[j] - (float)h0);                \
        const _Float16 h1 = (_Float16)x1[j];                              \
        xh[j + 4] = h1; xl[j + 4] = (_Float16)(x1[j] - (float)h1);        \
      }                                                                   \
      _Pragma("unroll")                                                   \
      for (int ct = 0; ct < 4; ++ct) {                                    \
        f16x8 bh = *(const f16x8*)&Ws[buf][(ks * 4 + ct) * 512 + lane * 8];       \
        f16x8 bl = *(const f16x8*)&Ws[buf][(8 + ks * 4 + ct) * 512 + lane * 8];   \
        acc[ct] = MFMA16(xh, bh, acc[ct], 0, 0, 0);                       \
        acc[ct] = MFMA16(xl, bh, acc[ct], 0, 0, 0);                       \
        acc[ct] = MFMA16(xh, bl, acc[ct], 0, 0, 0);                       \
      }                                                                   \
    }                                                                     \
  } while (0)

  // prologue: tiles 0,1 in flight (12 outstanding/thread)
  LOADT(xA, wA, 0);
  LOADT(xB, wB, 1);

#pragma unroll 1
  for (int kt = 0; kt < 12; kt += 2) {
    VMWAIT(6);                      // tile kt (set A) ready; kt+1 flying
    WWRITE(wA, 0);
    LGKMBAR();
    COMPUTET(xA, 0);
    LOADT(xA, wA, kt + 2);          // reissue AFTER consuming set A
    VMWAIT(6);                      // tile kt+1 (set B) ready
    WWRITE(wB, 1);
    LGKMBAR();
    COMPUTET(xB, 1);
    LOADT(xB, wB, kt + 3);
  }
  // tiles 12..15, draining ledger
  VMWAIT(6);  WWRITE(wA, 0);  LGKMBAR();  COMPUTET(xA, 0);  LOADT(xA, wA, 14);
  VMWAIT(6);  WWRITE(wB, 1);  LGKMBAR();  COMPUTET(xB, 1);  LOADT(xB, wB, 15);
  VMWAIT(6);  WWRITE(wA, 0);  LGKMBAR();  COMPUTET(xA, 0);
  VMWAIT(0);  WWRITE(wB, 1);  LGKMBAR();  COMPUTET(xB, 1);
#undef LOADT
#undef WWRITE
#undef COMPUTET

  // epilogue: C layout col=lane&15, row=(lane>>4)*4+r
  const size_t orow0 = (size_t)bm + w * 16 + (lane >> 4) * 4;
  if (which < 2) {
    _Float16* oh = (which == 0) ? qh : kh;
    _Float16* ol = (which == 0) ? ql : kl;
#pragma unroll
    for (int ct = 0; ct < 4; ++ct)
#pragma unroll
      for (int r = 0; r < 4; ++r) {
        const float y = acc[ct][r];
        const _Float16 h = (_Float16)y;
        const size_t idx = (orow0 + r) * HD + ct * 16 + (lane & 15);
        oh[idx] = h;
        ol[idx] = (_Float16)(y - (float)h);
      }
  } else {
    const int batch = (int)(orow0 >> 12);
    const int pos = (int)(orow0 & 4095);
#pragma unroll
    for (int ct = 0; ct < 4; ++ct) {
      f16x4 hv;
#pragma unroll
      for (int r = 0; r < 4; ++r) hv[r] = (_Float16)acc[ct][r];
      *(f16x4*)&vt[((size_t)batch * HD + ct * 16 + (lane & 15)) * SEQ + pos] = hv;
    }
  }
}

// ---------- flash attention, fp16x3 QK + f16 PV, split-4 partials ----------
// grid (128, 4): x -> pair p=x>>2 (q-blocks p and 63-p), parity s=x&3.
__global__ __launch_bounds__(256) void attn_kernel(
    const _Float16* __restrict__ qh, const _Float16* __restrict__ ql,
    const _Float16* __restrict__ kh, const _Float16* __restrict__ kl,
    const _Float16* __restrict__ vt,
    _Float16* __restrict__ opart, float* __restrict__ mlp)
{
  __shared__ __attribute__((aligned(16))) _Float16 Ksh[64 * 64];
  __shared__ __attribute__((aligned(16))) _Float16 Ksl[64 * 64];
  __shared__ __attribute__((aligned(16))) _Float16 Vs [64 * 64];
  __shared__ __attribute__((aligned(16))) _Float16 Pt [64 * 64];

  const int t = threadIdx.x, lane = t & 63, w = t >> 6;
  const int b = blockIdx.y;
  const int p = blockIdx.x >> 2, s = blockIdx.x & 3;
  const size_t bS = (size_t)b * SEQ;

  for (int sel = 0; sel < 2; ++sel) {
    const int qb = sel ? (63 - p) : p;
    const int qrow0 = qb * 64 + w * 16;
    const int nt = (qb >= s) ? ((qb - s) >> 2) + 1 : 0;  // kv tiles ≡ s mod 4

    float m[4] = {-INFINITY, -INFINITY, -INFINITY, -INFINITY};
    float lsum[4] = {0.f, 0.f, 0.f, 0.f};
    f32x4 o[4] = {{0,0,0,0},{0,0,0,0},{0,0,0,0},{0,0,0,0}};

    if (nt > 0) {
      const _Float16* qhp = qh + (bS + qrow0 + (lane & 15)) * HD + ((lane >> 4) * 8);
      const _Float16* qlp = ql + (bS + qrow0 + (lane & 15)) * HD + ((lane >> 4) * 8);
      f16x8 qhf[2], qlf[2];
      qhf[0] = *(const f16x8*)(qhp);      qhf[1] = *(const f16x8*)(qhp + 32);
      qlf[0] = *(const f16x8*)(qlp);      qlf[1] = *(const f16x8*)(qlp + 32);

      for (int i = 0; i < nt; ++i) {
        const int kt = s + 4 * i;
        const int j0 = kt * 64;

        __syncthreads();  // previous tile's LDS reads complete
#pragma unroll
        for (int c = 0; c < 2; ++c) {
          const int lin = t + 256 * c;
          const int row = lin >> 3, d8 = (lin & 7) * 8;
          const int dst = SW(row, d8);
          *(f16x8*)&Ksh[dst] = *(const f16x8*)&kh[(bS + j0 + row) * HD + d8];
          *(f16x8*)&Ksl[dst] = *(const f16x8*)&kl[(bS + j0 + row) * HD + d8];
          *(f16x8*)&Vs[dst]  = *(const f16x8*)&vt[((size_t)b * HD + row) * SEQ + j0 + d8];
        }
        __syncthreads();

        // ---- QK^T: fp16x3
        f32x4 sacc[4] = {{0,0,0,0},{0,0,0,0},{0,0,0,0},{0,0,0,0}};
#pragma unroll
        for (int kk = 0; kk < 2; ++kk)
#pragma unroll
          for (int kt4 = 0; kt4 < 4; ++kt4) {
            const int ba = SW(kt4 * 16 + (lane & 15), kk * 32 + (lane >> 4) * 8);
            f16x8 bh = *(const f16x8*)&Ksh[ba];
            f16x8 bl = *(const f16x8*)&Ksl[ba];
            sacc[kt4] = MFMA16(qhf[kk], bh, sacc[kt4], 0, 0, 0);
            sacc[kt4] = MFMA16(qlf[kk], bh, sacc[kt4], 0, 0, 0);
            sacc[kt4] = MFMA16(qhf[kk], bl, sacc[kt4], 0, 0, 0);
          }

        // ---- causal mask on the diagonal tile
        if (kt == qb) {
#pragma unroll
          for (int kt4 = 0; kt4 < 4; ++kt4) {
            const int key = j0 + kt4 * 16 + (lane & 15);
#pragma unroll
            for (int r = 0; r < 4; ++r)
              if (key > qrow0 + (lane >> 4) * 4 + r) sacc[kt4][r] = -INFINITY;
          }
        }

        // ---- online softmax (exp2 domain), P -> LDS f16
        float alf[4];
#pragma unroll
        for (int r = 0; r < 4; ++r) {
          float mx = fmaxf(fmaxf(sacc[0][r], sacc[1][r]),
                           fmaxf(sacc[2][r], sacc[3][r]));
          mx = fmaxf(mx, __shfl_xor(mx, 1));
          mx = fmaxf(mx, __shfl_xor(mx, 2));
          mx = fmaxf(mx, __shfl_xor(mx, 4));
          mx = fmaxf(mx, __shfl_xor(mx, 8));
          const float mn = fmaxf(m[r], mx);
          const float al = exp2f(m[r] - mn);
          const int prow = w * 16 + (lane >> 4) * 4 + r;
          float ps = 0.f;
#pragma unroll
          for (int kt4 = 0; kt4 < 4; ++kt4) {
            const _Float16 ph = (_Float16)exp2f(sacc[kt4][r] - mn);
            ps += (float)ph;
            Pt[SW(prow, kt4 * 16 + (lane & 15))] = ph;
          }
          ps += __shfl_xor(ps, 1);
          ps += __shfl_xor(ps, 2);
          ps += __shfl_xor(ps, 4);
          ps += __shfl_xor(ps, 8);
          lsum[r] = lsum[r] * al + ps;
          m[r] = mn;
          alf[r] = al;
        }
        const f32x4 av = {alf[0], alf[1], alf[2], alf[3]};
#pragma unroll
        for (int ct = 0; ct < 4; ++ct) o[ct] *= av;

        // ---- PV (per-wave Pt region)
#pragma unroll
        for (int kk = 0; kk < 2; ++kk) {
          f16x8 pa = *(const f16x8*)&Pt[SW(w * 16 + (lane & 15),
                                           kk * 32 + (lane >> 4) * 8)];
#pragma unroll
          for (int ct = 0; ct < 4; ++ct) {
            f16x8 vb = *(const f16x8*)&Vs[SW(ct * 16 + (lane & 15),
                                             kk * 32 + (lane >> 4) * 8)];
            o[ct] = MFMA16(pa, vb, o[ct], 0, 0, 0);
          }
        }
      }
    }

    // ---- write partials: normalized o (f16) + (m, l) f32
    f32x4 invv;
#pragma unroll
    for (int r = 0; r < 4; ++r) invv[r] = (nt > 0) ? 1.0f / lsum[r] : 0.0f;
    const size_t ridx0 = (size_t)(b * NSPLIT + s) * SEQ + qrow0 + (lane >> 4) * 4;
#pragma unroll
    for (int ct = 0; ct < 4; ++ct)
#pragma unroll
      for (int r = 0; r < 4; ++r)
        opart[(ridx0 + r) * HD + ct * 16 + (lane & 15)] =
            (_Float16)(o[ct][r] * invv[r]);
    if ((lane & 15) == 0) {
#pragma unroll
      for (int r = 0; r < 4; ++r) {
        mlp[(ridx0 + r) * 2]     = m[r];
        mlp[(ridx0 + r) * 2 + 1] = lsum[r];
      }
    }
  }
}

// ---------- combine the 4 kv-parity partials -------------------------------
__global__ __launch_bounds__(256) void combine_kernel(
    const _Float16* __restrict__ opart, const float* __restrict__ mlp,
    float* __restrict__ out)
{
  const int g = blockIdx.x * 256 + threadIdx.x;   // 262144
  const int row = g >> 4;
  const int cq = (g & 15) * 4;
  const int b = row >> 12, pos = row & 4095;

  float mv[4], lv[4], msx = -INFINITY;
#pragma unroll
  for (int s = 0; s < 4; ++s) {
    const size_t ri = (size_t)(b * NSPLIT + s) * SEQ + pos;
    mv[s] = mlp[ri * 2];
    lv[s] = mlp[ri * 2 + 1];
    msx = fmaxf(msx, mv[s]);
  }
  f32x4 num = {0.f, 0.f, 0.f, 0.f};
  float L = 0.f;
#pragma unroll
  for (int s = 0; s < 4; ++s) {
    const float wgt = lv[s] * exp2f(mv[s] - msx);
    L += wgt;
    const size_t ri = (size_t)(b * NSPLIT + s) * SEQ + pos;
    const f16x4 ov = *(const f16x4*)&opart[ri * HD + cq];
#pragma unroll
    for (int j = 0; j < 4; ++j) num[j] += wgt * (float)ov[j];
  }
  const float inv = 1.0f / L;
  f32x4 res = {num[0] * inv, num[1] * inv, num[2] * inv, num[3] * inv};
  *(f32x4*)&out[(size_t)row * HD + cq] = res;
}

extern "C" void kernel_launch(void* const* d_in, const int* in_sizes, int n_in,
                              void* d_out, int out_size, void* d_ws, size_t ws_size,
                              hipStream_t stream) {
  const float* query = (const float*)d_in[0];
  const float* key   = (const float*)d_in[1];
  const float* value = (const float*)d_in[2];
  const float* Wq    = (const float*)d_in[3];
  const float* Wk    = (const float*)d_in[4];
  const float* Wv    = (const float*)d_in[5];
  // d_in[6]: causal mask, handled analytically.

  float* out = (float*)d_out;

  _Float16* qh  = (_Float16*)d_ws;
  _Float16* ql  = qh  + (size_t)NB * SEQ * HD;
  _Float16* kh  = ql  + (size_t)NB * SEQ * HD;
  _Float16* kl  = kh  + (size_t)NB * SEQ * HD;
  _Float16* vt  = kl  + (size_t)NB * SEQ * HD;           // [b][64][4096]
  _Float16* wf  = vt  + (size_t)NB * SEQ * HD;           // [3][16][16][512]
  _Float16* opart = wf + (size_t)3 * 16 * 8192;          // [b*4+s][4096][64]
  float* mlp = (float*)(opart + (size_t)NB * NSPLIT * SEQ * HD);

  wsplit_kernel<<<dim3(3, 16), 256, 0, stream>>>(Wq, Wk, Wv, wf);
  proj_kernel<<<dim3(128, 3), 512, 0, stream>>>(query, key, value, wf,
                                                qh, ql, kh, kl, vt);
  attn_kernel<<<dim3(128, NB), 256, 0, stream>>>(qh, ql, kh, kl, vt, opart, mlp);
  combine_kernel<<<1024, 256, 0, stream>>>(opart, mlp, out);
}

// Round 15
// 89.622 us; speedup vs baseline: 1.1519x; 1.0872x over previous
//
#include <hip/hip_runtime.h>
#include <math.h>

// HeadAttention B=4, S=4096, D=1024, DK=DV=64, fp32 in/out, causal.
// Round 15: REVERT to the round-12 configuration (best measured total,
// 90.7us). R13 (1KB-span X) and R14 (M=128 density) both spilled their
// named staging sets (VGPR 80/52 < required) and regressed totals. Nine
// falsified proj theories across 14 rounds: staging mechanism, pipeline
// depth, barriers, occupancy, W-route, fetch span, work density -- all
// perf-neutral; proj is pinned at ~82-90us (~2.4 TB/s delivered input BW)
// by something below counter visibility (likely DRAM channel behavior of
// the 4KB-strided row access shared by every tiling). R12 config: BK=32,
// 32KB LDS (3 resident blocks/CU), depth-1 counted staging, VGPR=44 (no
// spills). attn / combine / wsplit as always.

#define SEQ 4096
#define DIM 1024
#define HD  64
#define NB  4
#define NSPLIT 4

typedef __attribute__((ext_vector_type(4))) float    f32x4;
typedef __attribute__((ext_vector_type(8))) _Float16 f16x8;
typedef __attribute__((ext_vector_type(4))) _Float16 f16x4;

#define MFMA16 __builtin_amdgcn_mfma_f32_16x16x32_f16

// swizzled offset into a [row][64] f16 LDS tile (attn): XOR 16B-chunk with row&7
__device__ __forceinline__ int SW(int row, int k) {
  return row * 64 + (k ^ ((row & 7) << 3));
}

// ---------- W pre-split into fragment-linear layout ------------------------
// wf[((which*16+kt)*16 + slot)*512 + lane*8 + j]:
//   slot s=ks*4+ct (0..7) hi-frag, s+8 lo-frag;
//   element = W[k][col]*scale, col=ct*16+(lane&15), k=kt*64+ks*32+(lane>>4)*8+j
__global__ __launch_bounds__(256) void wsplit_kernel(
    const float* __restrict__ Wq, const float* __restrict__ Wk,
    const float* __restrict__ Wv, _Float16* __restrict__ wf)
{
  const int which = blockIdx.x;   // 0..2
  const int kt    = blockIdx.y;   // 0..15
  const float* __restrict__ W = (which == 0) ? Wq : (which == 1) ? Wk : Wv;
  const float scale = (which == 0) ? 0.18033688011112042f : 1.0f;  // log2(e)/8
  const size_t tb = ((size_t)which * 16 + kt) * 8192;
#pragma unroll
  for (int i = 0; i < 2; ++i) {
    const int pair = threadIdx.x + 256 * i;   // 0..511
    const int lane = pair & 63, f = pair >> 6;  // f = ks*4+ct in 0..7
    const int ks = f >> 2, ct = f & 3;
    const int col = ct * 16 + (lane & 15);
    const int k0 = kt * 64 + ks * 32 + (lane >> 4) * 8;
    f16x8 hv, lv;
#pragma unroll
    for (int j = 0; j < 8; ++j) {
      const float y = W[(size_t)(k0 + j) * HD + col] * scale;
      const _Float16 h = (_Float16)y;
      hv[j] = h;
      lv[j] = (_Float16)(y - (float)h);
    }
    *(f16x8*)&wf[tb + (size_t)f * 512 + lane * 8]       = hv;
    *(f16x8*)&wf[tb + (size_t)(8 + f) * 512 + lane * 8] = lv;
  }
}

// ---------- projection: LDS-shared W, BK=32, 3 resident blocks/CU ----------
// grid (256, 3), 256 threads (4 waves, 64 output rows). 32 K-steps of 32.
// Per step: vmcnt(0) -> 4 ds_write (2 b128 X + 2 b128 W) -> issue next
// step's 4 loads -> lgkmcnt(0)+s_barrier -> 10 ds_read_b128 + 12 MFMA.
// LDS 32 KB -> 5 blocks by LDS, 3 assigned -> all resident (12 waves/CU).
__global__ __launch_bounds__(256, 3) void proj_kernel(
    const float* __restrict__ Xq, const float* __restrict__ Xk,
    const float* __restrict__ Xv,
    const _Float16* __restrict__ wf,
    _Float16* __restrict__ qh, _Float16* __restrict__ ql,
    _Float16* __restrict__ kh, _Float16* __restrict__ kl,
    _Float16* __restrict__ vt)
{
  __shared__ __attribute__((aligned(16))) float    Xs[2][64 * 32];  // 8 KB ea
  __shared__ __attribute__((aligned(16))) _Float16 Ws[2][4096];     // 8 KB ea

  const int which = blockIdx.y;
  const float* __restrict__ X = (which == 0) ? Xq : (which == 1) ? Xk : Xv;

  const int t = threadIdx.x, lane = t & 63, w = t >> 6;
  const int bm = blockIdx.x * 64;

  // X: thread t covers row t>>2 (each wave writes its own 16 rows), 16B
  // chunks c0=(t&3)*2, c0+1 of the 128B row-slice; XOR-swizzled LDS slots.
  const int xrow = t >> 2;
  const int xc   = (t & 3) * 2;
  const float* gX = X + (size_t)(bm + xrow) * DIM + xc * 4;  // +st*32/step
  const int xd0 = xrow * 32 + ((xc ^ (xrow & 7)) * 4);
  const int xd1 = xrow * 32 + (((xc + 1) ^ (xrow & 7)) * 4);

  // W: half-tile = hi 4KB (slots ks*4..+3) + lo 4KB (slots 8+ks*4..+3),
  // both contiguous in wf. Thread covers region r=t>>7 (hi/lo), 32B at
  // (t&127)*16 f16. Waves 0-1 write hi, 2-3 write lo (barrier covers it).
  const int wr = t >> 7;
  const int wi = (t & 127) * 16;
  const _Float16* gW = wf + (size_t)which * 131072 + wr * 4096 + wi;
  const int wd = wr * 2048 + wi;

  // read side: lane's A-frag row and k-chunks
  const int frow = lane & 15;
  const int ldsrow = w * 16 + frow;
  const int kc = (lane >> 4) * 2;
  const int xr0 = ldsrow * 32 + ((kc ^ (ldsrow & 7)) * 4);
  const int xr1 = ldsrow * 32 + (((kc + 1) ^ (ldsrow & 7)) * 4);

  f32x4 acc[4] = {{0,0,0,0},{0,0,0,0},{0,0,0,0},{0,0,0,0}};
  f32x4 xg0, xg1;
  f16x8 wg0, wg1;

  auto loadTile = [&](int st) {
    const float* xb = gX + st * 32;
    xg0 = *(const f32x4*)(xb);
    xg1 = *(const f32x4*)(xb + 4);
    const _Float16* wb = gW + (st >> 1) * 8192 + (st & 1) * 2048;
    wg0 = *(const f16x8*)(wb);
    wg1 = *(const f16x8*)(wb + 8);
  };

  loadTile(0);
#pragma unroll 1
  for (int st = 0; st < 32; ++st) {
    const int buf = st & 1;
    asm volatile("s_waitcnt vmcnt(0)" ::: "memory");
    __builtin_amdgcn_sched_barrier(0);
    *(f32x4*)&Xs[buf][xd0] = xg0;
    *(f32x4*)&Xs[buf][xd1] = xg1;
    *(f16x8*)&Ws[buf][wd]     = wg0;
    *(f16x8*)&Ws[buf][wd + 8] = wg1;
    if (st + 1 < 32) loadTile(st + 1);        // flies across the barrier
    asm volatile("s_waitcnt lgkmcnt(0)" ::: "memory");
    __builtin_amdgcn_sched_barrier(0);
    __builtin_amdgcn_s_barrier();
    __builtin_amdgcn_sched_barrier(0);

    // ---- compute this 32-k step
    f32x4 x0 = *(const f32x4*)&Xs[buf][xr0];
    f32x4 x1 = *(const f32x4*)&Xs[buf][xr1];
    f16x8 xh, xl;
#pragma unroll
    for (int j = 0; j < 4; ++j) {
      const _Float16 h0 = (_Float16)x0[j];
      xh[j] = h0; xl[j] = (_Float16)(x0[j] - (float)h0);
      const _Float16 h1 = (_Float16)x1[j];
      xh[j + 4] = h1; xl[j + 4] = (_Float16)(x1[j] - (float)h1);
    }
#pragma unroll
    for (int ct = 0; ct < 4; ++ct) {
      f16x8 bh = *(const f16x8*)&Ws[buf][ct * 512 + lane * 8];
      f16x8 bl = *(const f16x8*)&Ws[buf][2048 + ct * 512 + lane * 8];
      acc[ct] = MFMA16(xh, bh, acc[ct], 0, 0, 0);
      acc[ct] = MFMA16(xl, bh, acc[ct], 0, 0, 0);
      acc[ct] = MFMA16(xh, bl, acc[ct], 0, 0, 0);
    }
  }

  // epilogue: C layout col=lane&15, row=(lane>>4)*4+r
  const size_t orow0 = (size_t)bm + w * 16 + (lane >> 4) * 4;
  if (which < 2) {
    _Float16* oh = (which == 0) ? qh : kh;
    _Float16* ol = (which == 0) ? ql : kl;
#pragma unroll
    for (int ct = 0; ct < 4; ++ct)
#pragma unroll
      for (int r = 0; r < 4; ++r) {
        const float y = acc[ct][r];
        const _Float16 h = (_Float16)y;
        const size_t idx = (orow0 + r) * HD + ct * 16 + (lane & 15);
        oh[idx] = h;
        ol[idx] = (_Float16)(y - (float)h);
      }
  } else {
    const int batch = (int)(orow0 >> 12);
    const int pos = (int)(orow0 & 4095);
#pragma unroll
    for (int ct = 0; ct < 4; ++ct) {
      f16x4 hv;
#pragma unroll
      for (int r = 0; r < 4; ++r) hv[r] = (_Float16)acc[ct][r];
      *(f16x4*)&vt[((size_t)batch * HD + ct * 16 + (lane & 15)) * SEQ + pos] = hv;
    }
  }
}

// ---------- flash attention, fp16x3 QK + f16 PV, split-4 partials ----------
// grid (128, 4): x -> pair p=x>>2 (q-blocks p and 63-p), parity s=x&3.
__global__ __launch_bounds__(256) void attn_kernel(
    const _Float16* __restrict__ qh, const _Float16* __restrict__ ql,
    const _Float16* __restrict__ kh, const _Float16* __restrict__ kl,
    const _Float16* __restrict__ vt,
    _Float16* __restrict__ opart, float* __restrict__ mlp)
{
  __shared__ __attribute__((aligned(16))) _Float16 Ksh[64 * 64];
  __shared__ __attribute__((aligned(16))) _Float16 Ksl[64 * 64];
  __shared__ __attribute__((aligned(16))) _Float16 Vs [64 * 64];
  __shared__ __attribute__((aligned(16))) _Float16 Pt [64 * 64];

  const int t = threadIdx.x, lane = t & 63, w = t >> 6;
  const int b = blockIdx.y;
  const int p = blockIdx.x >> 2, s = blockIdx.x & 3;
  const size_t bS = (size_t)b * SEQ;

  for (int sel = 0; sel < 2; ++sel) {
    const int qb = sel ? (63 - p) : p;
    const int qrow0 = qb * 64 + w * 16;
    const int nt = (qb >= s) ? ((qb - s) >> 2) + 1 : 0;  // kv tiles ≡ s mod 4

    float m[4] = {-INFINITY, -INFINITY, -INFINITY, -INFINITY};
    float lsum[4] = {0.f, 0.f, 0.f, 0.f};
    f32x4 o[4] = {{0,0,0,0},{0,0,0,0},{0,0,0,0},{0,0,0,0}};

    if (nt > 0) {
      const _Float16* qhp = qh + (bS + qrow0 + (lane & 15)) * HD + ((lane >> 4) * 8);
      const _Float16* qlp = ql + (bS + qrow0 + (lane & 15)) * HD + ((lane >> 4) * 8);
      f16x8 qhf[2], qlf[2];
      qhf[0] = *(const f16x8*)(qhp);      qhf[1] = *(const f16x8*)(qhp + 32);
      qlf[0] = *(const f16x8*)(qlp);      qlf[1] = *(const f16x8*)(qlp + 32);

      for (int i = 0; i < nt; ++i) {
        const int kt = s + 4 * i;
        const int j0 = kt * 64;

        __syncthreads();  // previous tile's LDS reads complete
#pragma unroll
        for (int c = 0; c < 2; ++c) {
          const int lin = t + 256 * c;
          const int row = lin >> 3, d8 = (lin & 7) * 8;
          const int dst = SW(row, d8);
          *(f16x8*)&Ksh[dst] = *(const f16x8*)&kh[(bS + j0 + row) * HD + d8];
          *(f16x8*)&Ksl[dst] = *(const f16x8*)&kl[(bS + j0 + row) * HD + d8];
          *(f16x8*)&Vs[dst]  = *(const f16x8*)&vt[((size_t)b * HD + row) * SEQ + j0 + d8];
        }
        __syncthreads();

        // ---- QK^T: fp16x3
        f32x4 sacc[4] = {{0,0,0,0},{0,0,0,0},{0,0,0,0},{0,0,0,0}};
#pragma unroll
        for (int kk = 0; kk < 2; ++kk)
#pragma unroll
          for (int kt4 = 0; kt4 < 4; ++kt4) {
            const int ba = SW(kt4 * 16 + (lane & 15), kk * 32 + (lane >> 4) * 8);
            f16x8 bh = *(const f16x8*)&Ksh[ba];
            f16x8 bl = *(const f16x8*)&Ksl[ba];
            sacc[kt4] = MFMA16(qhf[kk], bh, sacc[kt4], 0, 0, 0);
            sacc[kt4] = MFMA16(qlf[kk], bh, sacc[kt4], 0, 0, 0);
            sacc[kt4] = MFMA16(qhf[kk], bl, sacc[kt4], 0, 0, 0);
          }

        // ---- causal mask on the diagonal tile
        if (kt == qb) {
#pragma unroll
          for (int kt4 = 0; kt4 < 4; ++kt4) {
            const int key = j0 + kt4 * 16 + (lane & 15);
#pragma unroll
            for (int r = 0; r < 4; ++r)
              if (key > qrow0 + (lane >> 4) * 4 + r) sacc[kt4][r] = -INFINITY;
          }
        }

        // ---- online softmax (exp2 domain), P -> LDS f16
        float alf[4];
#pragma unroll
        for (int r = 0; r < 4; ++r) {
          float mx = fmaxf(fmaxf(sacc[0][r], sacc[1][r]),
                           fmaxf(sacc[2][r], sacc[3][r]));
          mx = fmaxf(mx, __shfl_xor(mx, 1));
          mx = fmaxf(mx, __shfl_xor(mx, 2));
          mx = fmaxf(mx, __shfl_xor(mx, 4));
          mx = fmaxf(mx, __shfl_xor(mx, 8));
          const float mn = fmaxf(m[r], mx);
          const float al = exp2f(m[r] - mn);
          const int prow = w * 16 + (lane >> 4) * 4 + r;
          float ps = 0.f;
#pragma unroll
          for (int kt4 = 0; kt4 < 4; ++kt4) {
            const _Float16 ph = (_Float16)exp2f(sacc[kt4][r] - mn);
            ps += (float)ph;
            Pt[SW(prow, kt4 * 16 + (lane & 15))] = ph;
          }
          ps += __shfl_xor(ps, 1);
          ps += __shfl_xor(ps, 2);
          ps += __shfl_xor(ps, 4);
          ps += __shfl_xor(ps, 8);
          lsum[r] = lsum[r] * al + ps;
          m[r] = mn;
          alf[r] = al;
        }
        const f32x4 av = {alf[0], alf[1], alf[2], alf[3]};
#pragma unroll
        for (int ct = 0; ct < 4; ++ct) o[ct] *= av;

        // ---- PV (per-wave Pt region)
#pragma unroll
        for (int kk = 0; kk < 2; ++kk) {
          f16x8 pa = *(const f16x8*)&Pt[SW(w * 16 + (lane & 15),
                                           kk * 32 + (lane >> 4) * 8)];
#pragma unroll
          for (int ct = 0; ct < 4; ++ct) {
            f16x8 vb = *(const f16x8*)&Vs[SW(ct * 16 + (lane & 15),
                                             kk * 32 + (lane >> 4) * 8)];
            o[ct] = MFMA16(pa, vb, o[ct], 0, 0, 0);
          }
        }
      }
    }

    // ---- write partials: normalized o (f16) + (m, l) f32
    f32x4 invv;
#pragma unroll
    for (int r = 0; r < 4; ++r) invv[r] = (nt > 0) ? 1.0f / lsum[r] : 0.0f;
    const size_t ridx0 = (size_t)(b * NSPLIT + s) * SEQ + qrow0 + (lane >> 4) * 4;
#pragma unroll
    for (int ct = 0; ct < 4; ++ct)
#pragma unroll
      for (int r = 0; r < 4; ++r)
        opart[(ridx0 + r) * HD + ct * 16 + (lane & 15)] =
            (_Float16)(o[ct][r] * invv[r]);
    if ((lane & 15) == 0) {
#pragma unroll
      for (int r = 0; r < 4; ++r) {
        mlp[(ridx0 + r) * 2]     = m[r];
        mlp[(ridx0 + r) * 2 + 1] = lsum[r];
      }
    }
  }
}

// ---------- combine the 4 kv-parity partials -------------------------------
__global__ __launch_bounds__(256) void combine_kernel(
    const _Float16* __restrict__ opart, const float* __restrict__ mlp,
    float* __restrict__ out)
{
  const int g = blockIdx.x * 256 + threadIdx.x;   // 262144
  const int row = g >> 4;
  const int cq = (g & 15) * 4;
  const int b = row >> 12, pos = row & 4095;

  float mv[4], lv[4], msx = -INFINITY;
#pragma unroll
  for (int s = 0; s < 4; ++s) {
    const size_t ri = (size_t)(b * NSPLIT + s) * SEQ + pos;
    mv[s] = mlp[ri * 2];
    lv[s] = mlp[ri * 2 + 1];
    msx = fmaxf(msx, mv[s]);
  }
  f32x4 num = {0.f, 0.f, 0.f, 0.f};
  float L = 0.f;
#pragma unroll
  for (int s = 0; s < 4; ++s) {
    const float wgt = lv[s] * exp2f(mv[s] - msx);
    L += wgt;
    const size_t ri = (size_t)(b * NSPLIT + s) * SEQ + pos;
    const f16x4 ov = *(const f16x4*)&opart[ri * HD + cq];
#pragma unroll
    for (int j = 0; j < 4; ++j) num[j] += wgt * (float)ov[j];
  }
  const float inv = 1.0f / L;
  f32x4 res = {num[0] * inv, num[1] * inv, num[2] * inv, num[3] * inv};
  *(f32x4*)&out[(size_t)row * HD + cq] = res;
}

extern "C" void kernel_launch(void* const* d_in, const int* in_sizes, int n_in,
                              void* d_out, int out_size, void* d_ws, size_t ws_size,
                              hipStream_t stream) {
  const float* query = (const float*)d_in[0];
  const float* key   = (const float*)d_in[1];
  const float* value = (const float*)d_in[2];
  const float* Wq    = (const float*)d_in[3];
  const float* Wk    = (const float*)d_in[4];
  const float* Wv    = (const float*)d_in[5];
  // d_in[6]: causal mask, handled analytically.

  float* out = (float*)d_out;

  _Float16* qh  = (_Float16*)d_ws;
  _Float16* ql  = qh  + (size_t)NB * SEQ * HD;
  _Float16* kh  = ql  + (size_t)NB * SEQ * HD;
  _Float16* kl  = kh  + (size_t)NB * SEQ * HD;
  _Float16* vt  = kl  + (size_t)NB * SEQ * HD;           // [b][64][4096]
  _Float16* wf  = vt  + (size_t)NB * SEQ * HD;           // [3][16][16][512]
  _Float16* opart = wf + (size_t)3 * 16 * 8192;          // [b*4+s][4096][64]
  float* mlp = (float*)(opart + (size_t)NB * NSPLIT * SEQ * HD);

  wsplit_kernel<<<dim3(3, 16), 256, 0, stream>>>(Wq, Wk, Wv, wf);
  proj_kernel<<<dim3(256, 3), 256, 0, stream>>>(query, key, value, wf,
                                                qh, ql, kh, kl, vt);
  attn_kernel<<<dim3(128, NB), 256, 0, stream>>>(qh, ql, kh, kl, vt, opart, mlp);
  combine_kernel<<<1024, 256, 0, stream>>>(opart, mlp, out);
}